// Round 1
// baseline (119.387 us; speedup 1.0000x reference)
//
#include <hip/hip_runtime.h>
#include <hip/hip_bf16.h>
#include <stdint.h>

// ---------------------------------------------------------------------------
// MultiHeadedSelfAttention: x[2,2048,1024] -> out[2,2048,1024] (fp32)
// Pipeline: prep(bf16 casts, W^T, rope table) -> fused QKV GEMM (bf16 MFMA)
//           -> bias+RoPE epilogues -> banded flash attention (bf16 MFMA).
// ---------------------------------------------------------------------------

typedef __attribute__((ext_vector_type(8))) short bf16x8;
typedef __attribute__((ext_vector_type(4))) short bf16x4;
typedef __attribute__((ext_vector_type(4))) float f32x4;

#define DEV __device__ __forceinline__

DEV ushort f2b(float f) {               // fp32 -> bf16 bits, round-nearest-even
  union { float f; uint32_t u; } v; v.f = f;
  uint32_t r = v.u + 0x7FFFu + ((v.u >> 16) & 1u);
  return (ushort)(r >> 16);
}
DEV float b2f(ushort u) {
  union { uint32_t u; float f; } v; v.u = ((uint32_t)u) << 16;
  return v.f;
}

DEV void gload_lds16(const void* g, void* l) {
  // async global->LDS, 16B per lane; LDS dest is wave-uniform base + lane*16
  __builtin_amdgcn_global_load_lds((const __attribute__((address_space(1))) void*)g,
                                   (__attribute__((address_space(3))) void*)l,
                                   16, 0, 0);
}

// ---------------------------------------------------------------------------
// prep: x fp32 -> bf16 (vectorized)
__global__ __launch_bounds__(256) void prep_x_kernel(const float* __restrict__ x,
                                                     ushort* __restrict__ xb) {
  int t = blockIdx.x * 256 + threadIdx.x;          // 4096*1024/4 threads
  float4 v = ((const float4*)x)[t];
  bf16x4 o;
  o[0] = (short)f2b(v.x); o[1] = (short)f2b(v.y);
  o[2] = (short)f2b(v.z); o[3] = (short)f2b(v.w);
  *(bf16x4*)&xb[(size_t)t * 4] = o;
}

// prep: weights [1024][1024] fp32 -> wt[n(+which*1024)][k] bf16 (transposed)
__global__ void prep_w_kernel(const float* __restrict__ wq, const float* __restrict__ wk,
                              const float* __restrict__ wv, ushort* __restrict__ wt) {
  __shared__ float tile[32][33];
  int which = blockIdx.z;
  const float* w = which == 0 ? wq : (which == 1 ? wk : wv);
  int n0 = blockIdx.x * 32, k0 = blockIdx.y * 32;
  tile[threadIdx.y][threadIdx.x] = w[(size_t)(k0 + threadIdx.y) * 1024 + n0 + threadIdx.x];
  __syncthreads();
  wt[((size_t)which * 1024 + n0 + threadIdx.y) * 1024 + k0 + threadIdx.x] =
      f2b(tile[threadIdx.x][threadIdx.y]);
}

// prep: rope table [2048][32] of (cos, sin)
__global__ __launch_bounds__(256) void rope_tab_kernel(float2* __restrict__ tab) {
  int t = blockIdx.x * 256 + threadIdx.x;          // 65536
  int i = t & 31, s = t >> 5;
  float theta = powf(10000.0f, -(float)i / 32.0f);
  float ang = (float)s * theta;
  tab[t] = make_float2(cosf(ang), sinf(ang));
}

// ---------------------------------------------------------------------------
// QKV GEMM: A = xb [4096][1024] bf16, Bt = wt [3072][1024] bf16 -> C bf16 [4096][3072]
// m97 structure: 128x128 tile, BK=32, global_load_lds w=16, double-buffered.
__global__ __launch_bounds__(256) void qkv_gemm_kernel(const ushort* __restrict__ A,
                                                       const ushort* __restrict__ Bt,
                                                       ushort* __restrict__ C) {
  const int K = 1024, N = 3072;
  __shared__ alignas(16) ushort sA[2][128 * 32];
  __shared__ alignas(16) ushort sB[2][128 * 32];
  int tid = threadIdx.x;
  int bm = blockIdx.x, bn = blockIdx.y;
  int lane = tid & 63, wid = tid >> 6;
  int lhi = lane >> 4, llo = lane & 15;
  int wr = wid >> 1, wc = wid & 1;                 // 2x2 waves, 64x64 each

  const ushort* Abase = A + (size_t)bm * 128 * K;
  const ushort* Bbase = Bt + (size_t)bn * 128 * K;

  f32x4 acc[4][4];
#pragma unroll
  for (int i = 0; i < 4; ++i)
#pragma unroll
    for (int j = 0; j < 4; ++j) acc[i][j] = (f32x4){0.f, 0.f, 0.f, 0.f};

  auto stage = [&](int kt, int buf) {
    int k0 = kt * 32;
#pragma unroll
    for (int c = 0; c < 2; ++c) {
      int idx = c * 256 + tid;
      int row = idx >> 2, col = (idx & 3) * 8;
      gload_lds16(Abase + (size_t)row * K + k0 + col, &sA[buf][(idx & ~63) * 8]);
      gload_lds16(Bbase + (size_t)row * K + k0 + col, &sB[buf][(idx & ~63) * 8]);
    }
  };

  stage(0, 0);
  for (int kt = 0; kt < 32; ++kt) {
    __syncthreads();                               // staged tile kt now resident
    if (kt + 1 < 32) stage(kt + 1, (kt + 1) & 1);  // prefetch overlaps compute
    int buf = kt & 1;
    bf16x8 af[4], bfr[4];
#pragma unroll
    for (int mf = 0; mf < 4; ++mf)
      af[mf] = *(const bf16x8*)&sA[buf][(wr * 64 + mf * 16 + llo) * 32 + lhi * 8];
#pragma unroll
    for (int nf = 0; nf < 4; ++nf)
      bfr[nf] = *(const bf16x8*)&sB[buf][(wc * 64 + nf * 16 + llo) * 32 + lhi * 8];
#pragma unroll
    for (int mf = 0; mf < 4; ++mf)
#pragma unroll
      for (int nf = 0; nf < 4; ++nf)
        acc[mf][nf] = __builtin_amdgcn_mfma_f32_16x16x32_bf16(af[mf], bfr[nf], acc[mf][nf], 0, 0, 0);
  }
#pragma unroll
  for (int mf = 0; mf < 4; ++mf)
#pragma unroll
    for (int nf = 0; nf < 4; ++nf)
#pragma unroll
      for (int j = 0; j < 4; ++j) {
        int row = bm * 128 + wr * 64 + mf * 16 + lhi * 4 + j;
        int col = bn * 128 + wc * 64 + nf * 16 + llo;
        C[(size_t)row * N + col] = f2b(acc[mf][nf][j]);
      }
}

// ---------------------------------------------------------------------------
// epilogue: bias + RoPE for q and k; q pre-scaled by 1/sqrt(64)=0.125 (exact)
// C [4096][3072] bf16 -> qb, kb [32][2048][64] bf16
__global__ __launch_bounds__(256) void epi_qk_kernel(const ushort* __restrict__ C,
    const float* __restrict__ bq, const float* __restrict__ bk,
    const float2* __restrict__ tab,
    ushort* __restrict__ qb, ushort* __restrict__ kb) {
  int t = blockIdx.x * 256 + threadIdx.x;          // 4096*512
  int m = t >> 9, pp = t & 511;
  int s = m & 2047;
  int h = pp >> 5, i = pp & 31;
  float2 cs = tab[s * 32 + i];
  size_t crow = (size_t)m * 3072;
  int colq = h * 64 + 2 * i;
  float t0 = b2f(C[crow + colq]) + bq[colq];
  float t1 = b2f(C[crow + colq + 1]) + bq[colq + 1];
  float o0 = (t0 * cs.x - t1 * cs.y) * 0.125f;
  float o1 = (t1 * cs.x + t0 * cs.y) * 0.125f;
  int bh = (m >> 11) * 16 + h;
  size_t ooff = ((size_t)bh * 2048 + s) * 64 + 2 * i;
  qb[ooff] = f2b(o0); qb[ooff + 1] = f2b(o1);
  int colk = 1024 + colq;
  float u0 = b2f(C[crow + colk]) + bk[colq];
  float u1 = b2f(C[crow + colk + 1]) + bk[colq + 1];
  kb[ooff] = f2b(u0 * cs.x - u1 * cs.y);
  kb[ooff + 1] = f2b(u1 * cs.x + u0 * cs.y);
}

// epilogue: bias + transpose for v: C cols [2048..3072) -> vt [32][64][2048] bf16
__global__ __launch_bounds__(256) void epi_v_kernel(const ushort* __restrict__ C,
    const float* __restrict__ bv, ushort* __restrict__ vt) {
  __shared__ float lv[64][65];
  int bh = blockIdx.y; int h = bh & 15;
  int s0 = blockIdx.x * 64;
  int tid = threadIdx.x;
  size_t mbase = (size_t)(bh >> 4) * 2048 + s0;
#pragma unroll
  for (int ph = 0; ph < 2; ++ph) {
    int idx = ph * 256 + tid;
    int row = idx >> 3, col = (idx & 7) * 8;
    bf16x8 v = *(const bf16x8*)&C[(mbase + row) * 3072 + 2048 + h * 64 + col];
#pragma unroll
    for (int e = 0; e < 8; ++e) lv[row][col + e] = b2f((ushort)v[e]);
  }
  __syncthreads();
#pragma unroll
  for (int ph = 0; ph < 2; ++ph) {
    int idx = ph * 256 + tid;
    int hd = idx >> 3, s8 = (idx & 7) * 8;
    float bias = bv[h * 64 + hd];
    bf16x8 o;
#pragma unroll
    for (int e = 0; e < 8; ++e) o[e] = (short)f2b(lv[s8 + e][hd] + bias);
    *(bf16x8*)&vt[((size_t)bh * 64 + hd) * 2048 + s0 + s8] = o;
  }
}

// ---------------------------------------------------------------------------
// banded flash attention. grid (32 q-tiles, 32 bh), 4 waves x 16 q-rows.
// K in LDS XOR-swizzled (G4); V^T / P pitch-40 padded; online softmax via
// 16-lane shfl_xor reductions; P routed C-layout -> A-layout through LDS.
__global__ __launch_bounds__(256) void attn_kernel(
    const ushort* __restrict__ qb, const ushort* __restrict__ kb,
    const ushort* __restrict__ vt, const int* __restrict__ kmask,
    const int* __restrict__ whist, float* __restrict__ out) {
  __shared__ alignas(16) ushort sK[32 * 64];       // [32 keys][64 hd], swizzled
  __shared__ alignas(16) ushort sV[64 * 40];       // [64 d][32 keys], pitch 40
  __shared__ alignas(16) ushort sP[4][16 * 40];    // per-wave [16 q][32 k], pitch 40
  int tid = threadIdx.x;
  int lane = tid & 63, wid = tid >> 6;
  int lhi = lane >> 4, llo = lane & 15;
  int bh = blockIdx.y;
  int b = bh >> 4;
  int q0 = blockIdx.x * 64;
  int qw0 = q0 + wid * 16;
  int W = *whist;                                  // max_history_len (512)

  const ushort* qptr = qb + (size_t)bh * 2048 * 64;
  const ushort* kptr = kb + (size_t)bh * 2048 * 64;
  const ushort* vptr = vt + (size_t)bh * 64 * 2048;

  bf16x8 qf0, qf1;                                 // Q A-frags (hd 0-31, 32-63)
  {
    size_t base = (size_t)(qw0 + llo) * 64 + lhi * 8;
    qf0 = *(const bf16x8*)&qptr[base];
    qf1 = *(const bf16x8*)&qptr[base + 32];
  }

  float m_[4], l_[4];
  f32x4 o[4];
#pragma unroll
  for (int j = 0; j < 4; ++j) { m_[j] = -1e30f; l_[j] = 0.f; }
#pragma unroll
  for (int nf = 0; nf < 4; ++nf) o[nf] = (f32x4){0.f, 0.f, 0.f, 0.f};

  int lo = q0 - (W - 1); if (lo < 0) lo = 0;
  int jt0 = lo & ~31;
  const int* mrow = kmask + b * 2048;

  for (int jt = jt0; jt <= q0 + 63; jt += 32) {
    { // stage K (32x64, XOR-swizzled 16B slots) and V^T (64x32, pitch 40)
      int row = tid >> 3, slot = tid & 7;
      bf16x8 kvv = *(const bf16x8*)&kptr[(size_t)(jt + row) * 64 + slot * 8];
      *(bf16x8*)&sK[row * 64 + ((slot ^ (row & 7)) * 8)] = kvv;
      int vrow = tid >> 2, vslot = tid & 3;
      bf16x8 vvv = *(const bf16x8*)&vptr[(size_t)vrow * 2048 + jt + vslot * 8];
      *(bf16x8*)&sV[vrow * 40 + vslot * 8] = vvv;
    }
    __syncthreads();

    f32x4 sc0 = {0.f,0.f,0.f,0.f}, sc1 = {0.f,0.f,0.f,0.f};   // scores: keys 0-15, 16-31
#pragma unroll
    for (int ks = 0; ks < 2; ++ks) {
      int r0 = llo, r1 = 16 + llo;
      bf16x8 kf0 = *(const bf16x8*)&sK[r0 * 64 + (((ks * 4 + lhi) ^ (r0 & 7)) * 8)];
      bf16x8 kf1 = *(const bf16x8*)&sK[r1 * 64 + (((ks * 4 + lhi) ^ (r1 & 7)) * 8)];
      bf16x8 qq = ks ? qf1 : qf0;
      sc0 = __builtin_amdgcn_mfma_f32_16x16x32_bf16(qq, kf0, sc0, 0, 0, 0);
      sc1 = __builtin_amdgcn_mfma_f32_16x16x32_bf16(qq, kf1, sc1, 0, 0, 0);
    }

    int key0 = jt + llo;
    int msk0 = mrow[key0], msk1 = mrow[key0 + 16];
#pragma unroll
    for (int j = 0; j < 4; ++j) {
      int qi = qw0 + lhi * 4 + j;
      bool ok0 = (key0 <= qi) && (qi - key0 < W) && (msk0 == 0);
      bool ok1 = (key0 + 16 <= qi) && (qi - (key0 + 16) < W) && (msk1 == 0);
      float s0 = ok0 ? sc0[j] : -1e30f;
      float s1 = ok1 ? sc1[j] : -1e30f;
      float t = fmaxf(s0, s1);
      t = fmaxf(t, __shfl_xor(t, 1));
      t = fmaxf(t, __shfl_xor(t, 2));
      t = fmaxf(t, __shfl_xor(t, 4));
      t = fmaxf(t, __shfl_xor(t, 8));
      float mn = fmaxf(m_[j], t);
      float fac = __expf(m_[j] - mn);
      float p0 = ok0 ? __expf(sc0[j] - mn) : 0.f;  // p=0 on masked: no exp(-inf - -inf) NaN
      float p1 = ok1 ? __expf(sc1[j] - mn) : 0.f;
      float ps = p0 + p1;
      ps += __shfl_xor(ps, 1);
      ps += __shfl_xor(ps, 2);
      ps += __shfl_xor(ps, 4);
      ps += __shfl_xor(ps, 8);
      l_[j] = l_[j] * fac + ps;
      m_[j] = mn;
#pragma unroll
      for (int nf = 0; nf < 4; ++nf) o[nf][j] *= fac;
      int prow = lhi * 4 + j;
      sP[wid][prow * 40 + llo] = f2b(p0);
      sP[wid][prow * 40 + 16 + llo] = f2b(p1);
    }

    bf16x8 pf = *(const bf16x8*)&sP[wid][llo * 40 + lhi * 8];   // A-layout re-read
#pragma unroll
    for (int nf = 0; nf < 4; ++nf) {
      bf16x8 vf = *(const bf16x8*)&sV[(nf * 16 + llo) * 40 + lhi * 8];
      o[nf] = __builtin_amdgcn_mfma_f32_16x16x32_bf16(pf, vf, o[nf], 0, 0, 0);
    }
    __syncthreads();                               // before next tile restage
  }

#pragma unroll
  for (int j = 0; j < 4; ++j) {
    float inv = 1.f / l_[j];
    int qi = qw0 + lhi * 4 + j;
    size_t obase = ((size_t)b * 2048 + qi) * 1024 + (bh & 15) * 64 + llo;
#pragma unroll
    for (int nf = 0; nf < 4; ++nf)
      out[obase + nf * 16] = o[nf][j] * inv;
  }
}

// ---------------------------------------------------------------------------
extern "C" void kernel_launch(void* const* d_in, const int* in_sizes, int n_in,
                              void* d_out, int out_size, void* d_ws, size_t ws_size,
                              hipStream_t stream) {
  const float* x  = (const float*)d_in[0];
  const float* wq = (const float*)d_in[1];
  const float* bq = (const float*)d_in[2];
  const float* wk = (const float*)d_in[3];
  const float* bk = (const float*)d_in[4];
  const float* wv = (const float*)d_in[5];
  const float* bv = (const float*)d_in[6];
  const int* kmask = (const int*)d_in[7];
  const int* whist = (const int*)d_in[8];
  float* out = (float*)d_out;

  char* ws = (char*)d_ws;
  ushort* xb  = (ushort*)(ws);                       // [4096][1024] bf16   8 MB
  ushort* wt  = (ushort*)(ws + (8ull  << 20));       // [3072][1024] bf16   6 MB
  ushort* C   = (ushort*)(ws + (14ull << 20));       // [4096][3072] bf16  24 MB
  ushort* qb  = (ushort*)(ws + (38ull << 20));       // [32][2048][64]      8 MB
  ushort* kb  = (ushort*)(ws + (46ull << 20));       // [32][2048][64]      8 MB
  ushort* vt  = (ushort*)(ws + (54ull << 20));       // [32][64][2048]      8 MB
  float2* tab = (float2*)(ws + (62ull << 20));       // [2048][32] float2  .5 MB

  prep_x_kernel<<<4096, 256, 0, stream>>>(x, xb);
  prep_w_kernel<<<dim3(32, 32, 3), dim3(32, 32, 1), 0, stream>>>(wq, wk, wv, wt);
  rope_tab_kernel<<<256, 256, 0, stream>>>(tab);
  qkv_gemm_kernel<<<dim3(32, 24), 256, 0, stream>>>(xb, wt, C);
  epi_qk_kernel<<<8192, 256, 0, stream>>>(C, bq, bk, tab, qb, kb);
  epi_v_kernel<<<dim3(32, 32), 256, 0, stream>>>(C, bv, vt);
  attn_kernel<<<dim3(32, 32), 256, 0, stream>>>(qb, kb, vt, kmask, whist, out);
}